// Round 7
// baseline (146.401 us; speedup 1.0000x reference)
//
#include <hip/hip_runtime.h>
#include <math.h>

#define N_TOTAL 8192
#define BATCH   4096
#define DIMS    64
#define P1_BLOCKS 256
#define SEG     8
#define P2_BLOCKS 1088   // sum_{bc=0}^{127} ceil((bc+1)/8)

// ws layout (bytes):
//   0       double wd[66]     (0=sum sq norms, 1..64=col sums, 65=unused)
//   528     int cnt1; 532 int cnt2
//   544     float cs          (exp2 scale, written by pass1's last block)
//   1024    float partials[1088]
//   16384   float sq[8192]
//   65536   short Xh[8192*64]   (bf16 hi, row-major)
//   1114112 short Xl[8192*64]   (bf16 lo, row-major)

#if defined(__has_builtin)
#if __has_builtin(__builtin_amdgcn_exp2f)
#define EXP2F(x) __builtin_amdgcn_exp2f(x)
#endif
#endif
#ifndef EXP2F
#define EXP2F(x) exp2f(x)
#endif

typedef __attribute__((ext_vector_type(8))) short bf16x8;
typedef __attribute__((ext_vector_type(16))) float f32x16;
typedef __attribute__((ext_vector_type(4))) short s16x4;

__device__ inline short f2bf_rn(float x) {
    unsigned u = __float_as_uint(x);
    unsigned r = (u + 0x7fffu + ((u >> 16) & 1u)) >> 16;
    return (short)r;
}
__device__ inline float bf2f(short h) {
    return __uint_as_float(((unsigned)(unsigned short)h) << 16);
}

// pass1: fp32 -> bf16 hi/lo (once), row sq-norms, col sums; LAST block (fenced
// counter) computes the bandwidth scale -> csp. Replaces the scale_kernel node.
__global__ __launch_bounds__(256) void pass1_kernel(const float* __restrict__ src,
                                                    const float* __restrict__ tgt,
                                                    double* __restrict__ wd,
                                                    float* __restrict__ sqbuf,
                                                    short* __restrict__ Xh,
                                                    short* __restrict__ Xl,
                                                    int* __restrict__ cnt1,
                                                    float* __restrict__ csp) {
    __shared__ double cred[4][64];
    __shared__ double sred[4];
    __shared__ int s_last;
    const int t = threadIdx.x;
    const int lane = t & 63;
    const int wv = t >> 6;
    const int sub = lane >> 4;
    const int k4 = (lane & 15) << 2;
    const int gw = blockIdx.x * 4 + wv;
    const int numWaves = P1_BLOCKS * 4;

    double colacc[4] = {0.0, 0.0, 0.0, 0.0};
    double sqacc = 0.0;

    for (int g = gw; g < N_TOTAL / 4; g += numWaves) {
        int r = g * 4 + sub;
        const float* row = (r < BATCH) ? (src + (size_t)r * DIMS)
                                       : (tgt + (size_t)(r - BATCH) * DIMS);
        float4 v = *(const float4*)(row + k4);
        float xs[4] = {v.x, v.y, v.z, v.w};
        s16x4 h, l;
        float ssum = 0.f;
        #pragma unroll
        for (int i = 0; i < 4; ++i) {
            short hh = f2bf_rn(xs[i]);
            h[i] = hh;
            l[i] = f2bf_rn(xs[i] - bf2f(hh));
            colacc[i] += (double)xs[i];
            ssum = fmaf(xs[i], xs[i], ssum);
        }
        *(s16x4*)(Xh + (size_t)r * DIMS + k4) = h;
        *(s16x4*)(Xl + (size_t)r * DIMS + k4) = l;
        ssum += __shfl_xor(ssum, 1, 64);
        ssum += __shfl_xor(ssum, 2, 64);
        ssum += __shfl_xor(ssum, 4, 64);
        ssum += __shfl_xor(ssum, 8, 64);
        if ((lane & 15) == 0) { sqbuf[r] = ssum; sqacc += (double)ssum; }
    }
    #pragma unroll
    for (int i = 0; i < 4; ++i) {
        colacc[i] += __shfl_xor(colacc[i], 16, 64);
        colacc[i] += __shfl_xor(colacc[i], 32, 64);
    }
    sqacc += __shfl_xor(sqacc, 16, 64);
    sqacc += __shfl_xor(sqacc, 32, 64);
    if (lane < 16) {
        #pragma unroll
        for (int i = 0; i < 4; ++i) cred[wv][lane * 4 + i] = colacc[i];
    }
    if (lane == 0) sred[wv] = sqacc;
    __syncthreads();
    if (wv == 0) {
        double c = (cred[0][lane] + cred[1][lane]) + (cred[2][lane] + cred[3][lane]);
        atomicAdd(&wd[1 + lane], c);
        if (lane == 0) atomicAdd(&wd[0], (sred[0] + sred[1]) + (sred[2] + sred[3]));
    }

    // fused scale: last block to finish computes cs from the completed sums
    __threadfence();
    if (t == 0) s_last = (atomicAdd(cnt1, 1) == P1_BLOCKS - 1) ? 1 : 0;
    __syncthreads();
    if (s_last && wv == 0) {
        __threadfence();
        double cv = atomicAdd(&wd[1 + lane], 0.0);   // coherent read
        double vv = cv * cv;
        #pragma unroll
        for (int off = 32; off > 0; off >>= 1) vv += __shfl_xor(vv, off, 64);
        if (lane == 0) {
            double sumsq = atomicAdd(&wd[0], 0.0);
            const double n = (double)N_TOTAL;
            double bw0 = (2.0 * n * sumsq - 2.0 * vv) / (n * n - n) * 0.25;
            csp[0] = (float)(-1.0 / (bw0 * 0.6931471805599453 * 16.0));
        }
    }
}

// pass2: 32x32x16 MFMA, no LDS in hot loop, B frags = 32 VGPRs register-resident,
// flat live-only grid, last block (fenced counter) reduces partials -> out.
__global__ __launch_bounds__(256, 3) void pass2_kernel(const short* __restrict__ Xh,
                                                       const short* __restrict__ Xl,
                                                       const float* __restrict__ sqbuf,
                                                       const float* __restrict__ csp,
                                                       float* __restrict__ partials,
                                                       int* __restrict__ cnt2,
                                                       float* __restrict__ out) {
    // decode flat id -> (bc, seg): band b has 8 bc values, each with b+1 segs
    const int f = blockIdx.x;
    int b = (int)((-1.0f + sqrtf(1.0f + (float)f)) * 0.5f);
    while (4 * (b + 1) * (b + 2) <= f) ++b;
    while (4 * b * (b + 1) > f) --b;
    const int rem = f - 4 * b * (b + 1);
    const int q = rem / (b + 1);
    const int bc = 8 * b + q;
    const int seg = rem - q * (b + 1);
    const int r0 = seg * SEG;
    const int r1 = (bc < r0 + SEG - 1) ? bc : r0 + SEG - 1;

    const int t = threadIdx.x;
    const int lane = t & 63, w = t >> 6;
    const int wrow = w >> 1, wcol = w & 1;     // 2x2 wave grid of 32x32 sub-tiles
    const int l31 = lane & 31, half = lane >> 5;

    const float cs = csp[0];
    const float c2 = -2.f * cs;

    // B fragments: 32 cols x K=64, hi+lo = 8 x bf16x8 = 32 VGPRs, loop-invariant
    bf16x8 bh[4], bl[4];
    const size_t brow = (size_t)(bc * 64 + wcol * 32 + l31) * DIMS + half * 8;
    #pragma unroll
    for (int kk = 0; kk < 4; ++kk) {
        bh[kk] = *(const bf16x8*)(Xh + brow + kk * 16);
        bl[kk] = *(const bf16x8*)(Xl + brow + kk * 16);
    }
    const float sb = sqbuf[bc * 64 + wcol * 32 + l31] * cs;

    const size_t aoff = (size_t)(wrow * 32 + l31) * DIMS + half * 8;
    float facc = 0.f;

    for (int r = r0; r <= r1; ++r) {
        const size_t abase = (size_t)r * 64 * DIMS + aoff;
        bf16x8 ah[4], al[4];
        #pragma unroll
        for (int kk = 0; kk < 4; ++kk) {
            ah[kk] = *(const bf16x8*)(Xh + abase + kk * 16);
            al[kk] = *(const bf16x8*)(Xl + abase + kk * 16);
        }
        // sa: C/D row = (reg&3) + 8*(reg>>2) + 4*half  -> 4 float4 loads
        const int sabase = r * 64 + wrow * 32 + half * 4;
        float4 sav[4];
        #pragma unroll
        for (int g = 0; g < 4; ++g)
            sav[g] = *(const float4*)(sqbuf + sabase + 8 * g);

        f32x16 acc;
        #pragma unroll
        for (int i = 0; i < 16; ++i) acc[i] = 0.f;
        #pragma unroll
        for (int kk = 0; kk < 4; ++kk) {
            // dot = Ah·Bh + Ah·Bl + Al·Bh   (lo·lo dropped, ~2^-18 rel)
            acc = __builtin_amdgcn_mfma_f32_32x32x16_bf16(ah[kk], bh[kk], acc, 0, 0, 0);
            acc = __builtin_amdgcn_mfma_f32_32x32x16_bf16(ah[kk], bl[kk], acc, 0, 0, 0);
            acc = __builtin_amdgcn_mfma_f32_32x32x16_bf16(al[kk], bh[kk], acc, 0, 0, 0);
        }

        float lsum = 0.f;
        #pragma unroll
        for (int g = 0; g < 4; ++g) {
            const float* sp = (const float*)&sav[g];
            #pragma unroll
            for (int p = 0; p < 4; ++p) {
                float t0 = fmaf(sp[p], cs, sb);
                t0 = fmaf(acc[g * 4 + p], c2, t0);
                // 1 exp2 + 4 squarings = all 5 bandwidth kernels
                float e4 = EXP2F(t0);
                float e3 = e4 * e4;
                float e2 = e3 * e3;
                float e1 = e2 * e2;
                float e0 = e1 * e1;
                lsum += ((e0 + e1) + (e2 + e3)) + e4;
            }
        }
        float sgn = ((r < 64) == (bc < 64)) ? 1.f : -1.f;
        float wt  = (r == bc) ? 1.f : 2.f;
        facc = fmaf(lsum, sgn * wt, facc);
    }

    #pragma unroll
    for (int off = 32; off > 0; off >>= 1) facc += __shfl_xor(facc, off, 64);
    __shared__ float s_wred[4];
    __shared__ int s_last;
    if (lane == 0) s_wred[w] = facc;
    __syncthreads();
    if (t == 0) {
        partials[f] = (s_wred[0] + s_wred[1]) + (s_wred[2] + s_wred[3]);
        __threadfence();
        s_last = (atomicAdd(cnt2, 1) == P2_BLOCKS - 1) ? 1 : 0;
    }
    __syncthreads();
    if (s_last) {                            // fused finalize in last block
        __threadfence();
        double acc = 0.0;
        #pragma unroll
        for (int i = 0; i < 5; ++i) {
            int idx = t + 256 * i;
            if (idx < P2_BLOCKS)
                acc += (double)atomicAdd(&partials[idx], 0.f);  // coherent read
        }
        #pragma unroll
        for (int off = 32; off > 0; off >>= 1) acc += __shfl_xor(acc, off, 64);
        __shared__ double s_red[4];
        if (lane == 0) s_red[w] = acc;
        __syncthreads();
        if (t == 0) {
            double g = (s_red[0] + s_red[1]) + (s_red[2] + s_red[3]);
            out[0] = (float)(g / ((double)BATCH * (double)BATCH));
        }
    }
}

extern "C" void kernel_launch(void* const* d_in, const int* in_sizes, int n_in,
                              void* d_out, int out_size, void* d_ws, size_t ws_size,
                              hipStream_t stream) {
    const float* src = (const float*)d_in[0];
    const float* tgt = (const float*)d_in[1];
    char* ws = (char*)d_ws;
    double* wd     = (double*)ws;
    int*    cnt1   = (int*)(ws + 528);
    int*    cnt2   = (int*)(ws + 532);
    float*  csp    = (float*)(ws + 544);
    float*  parts  = (float*)(ws + 1024);
    float*  sqbuf  = (float*)(ws + 16384);
    short*  Xh     = (short*)(ws + 65536);
    short*  Xl     = (short*)(ws + 1114112);

    hipMemsetAsync(d_ws, 0, 544, stream);   // zero wd + both counters

    pass1_kernel<<<P1_BLOCKS, 256, 0, stream>>>(src, tgt, wd, sqbuf, Xh, Xl,
                                                cnt1, csp);

    pass2_kernel<<<P2_BLOCKS, 256, 0, stream>>>(Xh, Xl, sqbuf, csp, parts,
                                                cnt2, (float*)d_out);
}

// Round 8
// 100.658 us; speedup vs baseline: 1.4544x; 1.4544x over previous
//
#include <hip/hip_runtime.h>
#include <math.h>

#define N_TOTAL 8192
#define BATCH   4096
#define DIMS    64
#define P1_BLOCKS 256
#define SEG     8
#define NSEG    16          // 128 row-tiles / SEG
#define NPART   2048        // 128 * NSEG

// ws layout (bytes):
//   0       double wd[66]    (0=sum sq norms, 1..64=col sums, 65=unused)
//   528     float  cs        (exp2 scale, written by scale_kernel)
//   1024    float  partials[2048]
//   16384   float  sq[8192]
//   65536   short  Xh[8192*64]  (bf16 hi, row-major)
//   1114112 short  Xl[8192*64]  (bf16 lo, row-major)

#if defined(__has_builtin)
#if __has_builtin(__builtin_amdgcn_exp2f)
#define EXP2F(x) __builtin_amdgcn_exp2f(x)
#endif
#endif
#ifndef EXP2F
#define EXP2F(x) exp2f(x)
#endif

typedef __attribute__((ext_vector_type(8))) short bf16x8;
typedef __attribute__((ext_vector_type(4))) float f32x4;
typedef __attribute__((ext_vector_type(4))) short s16x4;

__device__ inline short f2bf_rn(float x) {
    unsigned u = __float_as_uint(x);
    unsigned r = (u + 0x7fffu + ((u >> 16) & 1u)) >> 16;
    return (short)r;
}
__device__ inline float bf2f(short h) {
    return __uint_as_float(((unsigned)(unsigned short)h) << 16);
}

// pass1: fp32 -> bf16 hi/lo split (once), row sq-norms, col sums for bandwidth
__global__ __launch_bounds__(256) void pass1_kernel(const float* __restrict__ src,
                                                    const float* __restrict__ tgt,
                                                    double* __restrict__ wd,
                                                    float* __restrict__ sqbuf,
                                                    short* __restrict__ Xh,
                                                    short* __restrict__ Xl) {
    __shared__ double cred[4][64];
    __shared__ double sred[4];
    const int lane = threadIdx.x & 63;
    const int wv = threadIdx.x >> 6;
    const int sub = lane >> 4;
    const int k4 = (lane & 15) << 2;
    const int gw = blockIdx.x * 4 + wv;
    const int numWaves = P1_BLOCKS * 4;

    double colacc[4] = {0.0, 0.0, 0.0, 0.0};
    double sqacc = 0.0;

    for (int g = gw; g < N_TOTAL / 4; g += numWaves) {
        int r = g * 4 + sub;
        const float* row = (r < BATCH) ? (src + (size_t)r * DIMS)
                                       : (tgt + (size_t)(r - BATCH) * DIMS);
        float4 v = *(const float4*)(row + k4);
        float xs[4] = {v.x, v.y, v.z, v.w};
        s16x4 h, l;
        float ssum = 0.f;
        #pragma unroll
        for (int i = 0; i < 4; ++i) {
            short hh = f2bf_rn(xs[i]);
            h[i] = hh;
            l[i] = f2bf_rn(xs[i] - bf2f(hh));
            colacc[i] += (double)xs[i];
            ssum = fmaf(xs[i], xs[i], ssum);
        }
        *(s16x4*)(Xh + (size_t)r * DIMS + k4) = h;
        *(s16x4*)(Xl + (size_t)r * DIMS + k4) = l;
        ssum += __shfl_xor(ssum, 1, 64);
        ssum += __shfl_xor(ssum, 2, 64);
        ssum += __shfl_xor(ssum, 4, 64);
        ssum += __shfl_xor(ssum, 8, 64);
        if ((lane & 15) == 0) { sqbuf[r] = ssum; sqacc += (double)ssum; }
    }
    #pragma unroll
    for (int i = 0; i < 4; ++i) {
        colacc[i] += __shfl_xor(colacc[i], 16, 64);
        colacc[i] += __shfl_xor(colacc[i], 32, 64);
    }
    sqacc += __shfl_xor(sqacc, 16, 64);
    sqacc += __shfl_xor(sqacc, 32, 64);
    if (lane < 16) {
        #pragma unroll
        for (int i = 0; i < 4; ++i) cred[wv][lane * 4 + i] = colacc[i];
    }
    if (lane == 0) sred[wv] = sqacc;
    __syncthreads();
    if (wv == 0) {
        double c = (cred[0][lane] + cred[1][lane]) + (cred[2][lane] + cred[3][lane]);
        atomicAdd(&wd[1 + lane], c);
        if (lane == 0) atomicAdd(&wd[0], (sred[0] + sred[1]) + (sred[2] + sred[3]));
    }
}

// one wave: bandwidth scale from pass1 sums (kernel boundary = visibility)
__global__ void scale_kernel(const double* __restrict__ wd, float* __restrict__ csp) {
    const int lane = threadIdx.x;
    double cv = wd[1 + lane];
    double vv = cv * cv;
    #pragma unroll
    for (int off = 32; off > 0; off >>= 1) vv += __shfl_xor(vv, off, 64);
    if (lane == 0) {
        const double n = (double)N_TOTAL;
        double bw0 = (2.0 * n * wd[0] - 2.0 * vv) / (n * n - n) * 0.25;
        csp[0] = (float)(-1.0 / (bw0 * 0.6931471805599453 * 16.0));
    }
}

// pass2: 512-thread blocks = 8 waves sharing one LDS B-tile.
// wave w: A-strip (w&3), tile-stream (w>>2) striding the segment by 2.
// Same per-wave body as the R5 38-us kernel; 2x resident waves per CU
// (LDS 37KB caps 4 blocks/CU; 8 waves/block -> 32 waves/CU).
__global__ __launch_bounds__(512) void pass2_kernel(const short* __restrict__ Xh,
                                                    const short* __restrict__ Xl,
                                                    const float* __restrict__ sqbuf,
                                                    const float* __restrict__ csp,
                                                    float* __restrict__ partials) {
    const int bc = blockIdx.x;
    const int r0 = blockIdx.y * SEG;
    const int pidx = blockIdx.y * 128 + bc;
    const int t = threadIdx.x;
    if (r0 > bc) {                        // dead block: zero its partial
        if (t == 0) partials[pidx] = 0.f;
        return;
    }
    const int r1 = (bc < r0 + SEG - 1) ? bc : r0 + SEG - 1;

    __shared__ __align__(16) short Bh[64][72];
    __shared__ __align__(16) short Bl[64][72];
    __shared__ float s_wred[8];

    const int lane = t & 63, w = t >> 6;
    const int strip = w & 3, ts = w >> 2;
    const int quad = lane >> 4, lrow = lane & 15;

    // stage B column-tile into LDS: 512 threads, one shot
    {
        int row = t >> 3;            // 0..63
        int c8 = (t & 7) << 3;       // short offset 0..56
        size_t gsrc = (size_t)(bc * 64 + row) * DIMS + c8;
        *(s16x4*)&Bh[row][c8]     = *(const s16x4*)(Xh + gsrc);
        *(s16x4*)&Bh[row][c8 + 4] = *(const s16x4*)(Xh + gsrc + 4);
        *(s16x4*)&Bl[row][c8]     = *(const s16x4*)(Xl + gsrc);
        *(s16x4*)&Bl[row][c8 + 4] = *(const s16x4*)(Xl + gsrc + 4);
    }
    const float cs = csp[0];
    const float c2 = -2.f * cs;
    float sbc[4];
    #pragma unroll
    for (int j = 0; j < 4; ++j)
        sbc[j] = sqbuf[bc * 64 + j * 16 + lrow] * cs;
    __syncthreads();

    const size_t aoff = (size_t)(strip * 16 + lrow) * DIMS + quad * 8;

    float facc = 0.f;

    for (int r = r0 + ts; r <= r1; r += 2) {
        const size_t abase = (size_t)r * 64 * DIMS + aoff;
        bf16x8 ah0 = *(const bf16x8*)(Xh + abase);
        bf16x8 ah1 = *(const bf16x8*)(Xh + abase + 32);
        bf16x8 al0 = *(const bf16x8*)(Xl + abase);
        bf16x8 al1 = *(const bf16x8*)(Xl + abase + 32);
        float4 csa = *(const float4*)(sqbuf + r * 64 + strip * 16 + quad * 4);

        f32x4 acc[4];
        #pragma unroll
        for (int j = 0; j < 4; ++j) acc[j] = (f32x4){0.f, 0.f, 0.f, 0.f};
        #pragma unroll
        for (int j = 0; j < 4; ++j) {
            const int brow = j * 16 + lrow;
            const int bcol = quad * 8;
            bf16x8 bh0 = *(const bf16x8*)&Bh[brow][bcol];
            bf16x8 bh1 = *(const bf16x8*)&Bh[brow][bcol + 32];
            bf16x8 bl0 = *(const bf16x8*)&Bl[brow][bcol];
            bf16x8 bl1 = *(const bf16x8*)&Bl[brow][bcol + 32];
            // dot = Ah·Bh + Ah·Bl + Al·Bh   (lo·lo dropped, ~2^-18 rel)
            acc[j] = __builtin_amdgcn_mfma_f32_16x16x32_bf16(ah0, bh0, acc[j], 0, 0, 0);
            acc[j] = __builtin_amdgcn_mfma_f32_16x16x32_bf16(ah1, bh1, acc[j], 0, 0, 0);
            acc[j] = __builtin_amdgcn_mfma_f32_16x16x32_bf16(ah0, bl0, acc[j], 0, 0, 0);
            acc[j] = __builtin_amdgcn_mfma_f32_16x16x32_bf16(ah1, bl1, acc[j], 0, 0, 0);
            acc[j] = __builtin_amdgcn_mfma_f32_16x16x32_bf16(al0, bh0, acc[j], 0, 0, 0);
            acc[j] = __builtin_amdgcn_mfma_f32_16x16x32_bf16(al1, bh1, acc[j], 0, 0, 0);
        }

        float sac[4] = {csa.x * cs, csa.y * cs, csa.z * cs, csa.w * cs};
        float lsum = 0.f;
        #pragma unroll
        for (int j = 0; j < 4; ++j) {
            #pragma unroll
            for (int p = 0; p < 4; ++p) {
                // t0 = -L2/(16*bw0*ln2); 1 exp2 + 4 squarings = 5 kernels
                float t0 = fmaf(acc[j][p], c2, sac[p] + sbc[j]);
                float e4 = EXP2F(t0);
                float e3 = e4 * e4;
                float e2 = e3 * e3;
                float e1 = e2 * e2;
                float e0 = e1 * e1;
                lsum += ((e0 + e1) + (e2 + e3)) + e4;
            }
        }
        float sgn = ((r < 64) == (bc < 64)) ? 1.f : -1.f;
        float wt  = (r == bc) ? 1.f : 2.f;
        facc = fmaf(lsum, sgn * wt, facc);
    }

    #pragma unroll
    for (int off = 32; off > 0; off >>= 1) facc += __shfl_xor(facc, off, 64);
    if (lane == 0) s_wred[w] = facc;
    __syncthreads();
    if (t == 0)
        partials[pidx] = ((s_wred[0] + s_wred[1]) + (s_wred[2] + s_wred[3]))
                       + ((s_wred[4] + s_wred[5]) + (s_wred[6] + s_wred[7]));
}

__global__ __launch_bounds__(256) void finalize_kernel(const float* __restrict__ partials,
                                                       float* __restrict__ out) {
    __shared__ double s_red[4];
    const int t = threadIdx.x;
    const int lane = t & 63, w = t >> 6;
    double acc = 0.0;
    #pragma unroll
    for (int i = 0; i < NPART / 256; ++i)
        acc += (double)partials[t + 256 * i];
    #pragma unroll
    for (int off = 32; off > 0; off >>= 1) acc += __shfl_xor(acc, off, 64);
    if (lane == 0) s_red[w] = acc;
    __syncthreads();
    if (t == 0) {
        double g = (s_red[0] + s_red[1]) + (s_red[2] + s_red[3]);
        out[0] = (float)(g / ((double)BATCH * (double)BATCH));
    }
}

extern "C" void kernel_launch(void* const* d_in, const int* in_sizes, int n_in,
                              void* d_out, int out_size, void* d_ws, size_t ws_size,
                              hipStream_t stream) {
    const float* src = (const float*)d_in[0];
    const float* tgt = (const float*)d_in[1];
    char* ws = (char*)d_ws;
    double* wd     = (double*)ws;
    float*  csp    = (float*)(ws + 528);
    float*  parts  = (float*)(ws + 1024);
    float*  sqbuf  = (float*)(ws + 16384);
    short*  Xh     = (short*)(ws + 65536);
    short*  Xl     = (short*)(ws + 1114112);

    hipMemsetAsync(d_ws, 0, 544, stream);   // zero wd[0..64]

    pass1_kernel<<<P1_BLOCKS, 256, 0, stream>>>(src, tgt, wd, sqbuf, Xh, Xl);
    scale_kernel<<<1, 64, 0, stream>>>(wd, csp);

    dim3 grid(128, NSEG);
    pass2_kernel<<<grid, 512, 0, stream>>>(Xh, Xl, sqbuf, csp, parts);

    finalize_kernel<<<1, 256, 0, stream>>>(parts, (float*)d_out);
}